// Round 4
// baseline (659.283 us; speedup 1.0000x reference)
//
#include <hip/hip_runtime.h>

#define NT 512
#define SEQ_LEN 8192

static __device__ __forceinline__ float2 f2(float x, float y){ return make_float2(x,y); }
static __device__ __forceinline__ float2 cadd(float2 a, float2 b){ return f2(a.x+b.x, a.y+b.y); }
static __device__ __forceinline__ float2 csub(float2 a, float2 b){ return f2(a.x-b.x, a.y-b.y); }
static __device__ __forceinline__ float2 cmul(float2 a, float2 b){ return f2(a.x*b.x-a.y*b.y, a.x*b.y+a.y*b.x); }
static __device__ __forceinline__ float2 cmulc(float2 a, float2 b){ return f2(a.x*b.x+a.y*b.y, a.y*b.x-a.x*b.y); } // a*conj(b)
static __device__ __forceinline__ float2 mul_mi(float2 a){ return f2(a.y, -a.x); }  // a * (-i)
static __device__ __forceinline__ float2 mul_pi(float2 a){ return f2(-a.y, a.x); }  // a * (+i)
static __device__ __forceinline__ int swz(int e){ return e ^ ((e>>4)&15) ^ ((e>>8)&15); }
static __device__ __forceinline__ int rev13(int v){ return (int)(__brev((unsigned)v) >> 19); }

// ---------------- MLP: h3[j][16] = sin-MLP(z[j]) ----------------
__global__ void hyena_mlp(const float* __restrict__ z,
                          const float* __restrict__ W1, const float* __restrict__ b1,
                          const float* __restrict__ W2, const float* __restrict__ b2,
                          const float* __restrict__ W3, const float* __restrict__ b3,
                          const float* __restrict__ freq,
                          float* __restrict__ h3) {
    int j = blockIdx.x * blockDim.x + threadIdx.x;
    if (j >= SEQ_LEN) return;
    float z0 = z[3*j+0], z1 = z[3*j+1], z2 = z[3*j+2];
    float ha[16], hb[16];
#pragma unroll
    for (int o = 0; o < 16; ++o) {
        float acc = b1[o] + z0*W1[o] + z1*W1[16+o] + z2*W1[32+o];
        ha[o] = sinf(freq[o] * acc);
    }
#pragma unroll
    for (int p = 0; p < 16; ++p) {
        float acc = b2[p];
#pragma unroll
        for (int o = 0; o < 16; ++o) acc += ha[o] * W2[o*16+p];
        hb[p] = sinf(freq[p] * acc);
    }
#pragma unroll
    for (int q = 0; q < 16; ++q) {
        float acc = b3[q];
#pragma unroll
        for (int o = 0; o < 16; ++o) acc += hb[o] * W3[o*16+q];
        h3[j*16+q] = sinf(freq[q] * acc);
    }
}

// ------ 4-stage (radix-16-as-radix-2^4) register butterflies, slim twiddles ------
// Only t0..t3, u0, u1, v0(wb), wa are materialized; the -i-rotated partners are
// applied at the use site via mul_mi/mul_pi (2-op sign/swap, no extra VGPRs).
static __device__ __forceinline__ void dif4(float2 r[16], float2 wd){
    const float2 c1 = f2(0.9238795325112867f,-0.3826834323650898f);  // e^{-i pi/8}
    const float2 c2 = f2(0.7071067811865476f,-0.7071067811865476f);  // e^{-i pi/4}
    const float2 c3 = f2(0.3826834323650898f,-0.9238795325112867f);  // e^{-i 3pi/8}
    float2 wc = cmul(wd,wd), wb = cmul(wc,wc), wa = cmul(wb,wb);
    float2 t0 = wd, t1 = cmul(wd,c1), t2 = cmul(wd,c2), t3 = cmul(wd,c3);
    float2 u0 = wc, u1 = cmul(wc,c2);
    // stage A (stride 8)
    { float2 u=r[0], v=r[8];  r[0]=cadd(u,v); r[8] =cmul(csub(u,v), t0); }
    { float2 u=r[1], v=r[9];  r[1]=cadd(u,v); r[9] =cmul(csub(u,v), t1); }
    { float2 u=r[2], v=r[10]; r[2]=cadd(u,v); r[10]=cmul(csub(u,v), t2); }
    { float2 u=r[3], v=r[11]; r[3]=cadd(u,v); r[11]=cmul(csub(u,v), t3); }
    { float2 u=r[4], v=r[12]; r[4]=cadd(u,v); r[12]=mul_mi(cmul(csub(u,v), t0)); }
    { float2 u=r[5], v=r[13]; r[5]=cadd(u,v); r[13]=mul_mi(cmul(csub(u,v), t1)); }
    { float2 u=r[6], v=r[14]; r[6]=cadd(u,v); r[14]=mul_mi(cmul(csub(u,v), t2)); }
    { float2 u=r[7], v=r[15]; r[7]=cadd(u,v); r[15]=mul_mi(cmul(csub(u,v), t3)); }
    // stage B (stride 4)
#pragma unroll
    for (int b = 0; b < 16; b += 8) {
        { float2 u=r[b+0], v=r[b+4]; r[b+0]=cadd(u,v); r[b+4]=cmul(csub(u,v), u0); }
        { float2 u=r[b+1], v=r[b+5]; r[b+1]=cadd(u,v); r[b+5]=cmul(csub(u,v), u1); }
        { float2 u=r[b+2], v=r[b+6]; r[b+2]=cadd(u,v); r[b+6]=mul_mi(cmul(csub(u,v), u0)); }
        { float2 u=r[b+3], v=r[b+7]; r[b+3]=cadd(u,v); r[b+7]=mul_mi(cmul(csub(u,v), u1)); }
    }
    // stage C (stride 2)
#pragma unroll
    for (int b = 0; b < 16; b += 4) {
        { float2 u=r[b+0], v=r[b+2]; r[b+0]=cadd(u,v); r[b+2]=cmul(csub(u,v), wb); }
        { float2 u=r[b+1], v=r[b+3]; r[b+1]=cadd(u,v); r[b+3]=mul_mi(cmul(csub(u,v), wb)); }
    }
    // stage D (stride 1)
#pragma unroll
    for (int b = 0; b < 16; b += 2) { float2 u=r[b], v=r[b+1]; r[b]=cadd(u,v); r[b+1]=cmul(csub(u,v), wa); }
}
static __device__ __forceinline__ void dit4(float2 r[16], float2 wd){
    const float2 c1 = f2(0.9238795325112867f,-0.3826834323650898f);
    const float2 c2 = f2(0.7071067811865476f,-0.7071067811865476f);
    const float2 c3 = f2(0.3826834323650898f,-0.9238795325112867f);
    float2 wc = cmul(wd,wd), wb = cmul(wc,wc), wa = cmul(wb,wb);
    float2 t0 = wd, t1 = cmul(wd,c1), t2 = cmul(wd,c2), t3 = cmul(wd,c3);
    float2 u0 = wc, u1 = cmul(wc,c2);
    // stage D' (stride 1), conj(wa)
#pragma unroll
    for (int b = 0; b < 16; b += 2) { float2 u=r[b]; float2 t=cmulc(r[b+1], wa); r[b]=cadd(u,t); r[b+1]=csub(u,t); }
    // stage C' (stride 2): conj(wb) and conj(-i wb) = +i conj(wb)
#pragma unroll
    for (int b = 0; b < 16; b += 4) {
        { float2 u=r[b+0]; float2 t=cmulc(r[b+2], wb);         r[b+0]=cadd(u,t); r[b+2]=csub(u,t); }
        { float2 u=r[b+1]; float2 t=mul_pi(cmulc(r[b+3], wb)); r[b+1]=cadd(u,t); r[b+3]=csub(u,t); }
    }
    // stage B' (stride 4)
#pragma unroll
    for (int b = 0; b < 16; b += 8) {
        { float2 u=r[b+0]; float2 t=cmulc(r[b+4], u0);         r[b+0]=cadd(u,t); r[b+4]=csub(u,t); }
        { float2 u=r[b+1]; float2 t=cmulc(r[b+5], u1);         r[b+1]=cadd(u,t); r[b+5]=csub(u,t); }
        { float2 u=r[b+2]; float2 t=mul_pi(cmulc(r[b+6], u0)); r[b+2]=cadd(u,t); r[b+6]=csub(u,t); }
        { float2 u=r[b+3]; float2 t=mul_pi(cmulc(r[b+7], u1)); r[b+3]=cadd(u,t); r[b+7]=csub(u,t); }
    }
    // stage A' (stride 8)
    { float2 u=r[0]; float2 t=cmulc(r[8],  t0);        r[0]=cadd(u,t); r[8] =csub(u,t); }
    { float2 u=r[1]; float2 t=cmulc(r[9],  t1);        r[1]=cadd(u,t); r[9] =csub(u,t); }
    { float2 u=r[2]; float2 t=cmulc(r[10], t2);        r[2]=cadd(u,t); r[10]=csub(u,t); }
    { float2 u=r[3]; float2 t=cmulc(r[11], t3);        r[3]=cadd(u,t); r[11]=csub(u,t); }
    { float2 u=r[4]; float2 t=mul_pi(cmulc(r[12], t0)); r[4]=cadd(u,t); r[12]=csub(u,t); }
    { float2 u=r[5]; float2 t=mul_pi(cmulc(r[13], t1)); r[5]=cadd(u,t); r[13]=csub(u,t); }
    { float2 u=r[6]; float2 t=mul_pi(cmulc(r[14], t2)); r[6]=cadd(u,t); r[14]=csub(u,t); }
    { float2 u=r[7]; float2 t=mul_pi(cmulc(r[15], t3)); r[7]=cadd(u,t); r[15]=csub(u,t); }
}

// aligned pair access (positions p even; swz may flip parity, so select)
static __device__ __forceinline__ void readpair(const float2* cv, int p, float2& e0, float2& e1){
    int sp = swz(p);
    float4 q = *(const float4*)&cv[sp & ~1];
    float2 lo = f2(q.x,q.y), hi = f2(q.z,q.w);
    if (sp & 1) { e0 = hi; e1 = lo; } else { e0 = lo; e1 = hi; }
}
static __device__ __forceinline__ void writepair(float2* cv, int p, float2 e0, float2 e1){
    int sp = swz(p);
    float4 q;
    if (sp & 1) q = make_float4(e1.x,e1.y,e0.x,e0.y);
    else        q = make_float4(e0.x,e0.y,e1.x,e1.y);
    *(float4*)&cv[sp & ~1] = q;
}

static __device__ __forceinline__ float2 getw(const float2* T1, const float2* T2, int k){
    return cmul(T1[k>>6], T2[k&63]);   // e^{-i pi k / 8192}
}
// rfft unpack K[k], K[8192-k] packed as float4 (scaled by 1/16384, +bias*s on real parts)
static __device__ __forceinline__ float4 kpack(float2 Ck, float2 Cm, float2 w, float bds){
    const float s = 1.0f/16384.0f;
    float2 A  = f2(0.5f*(Ck.x+Cm.x), 0.5f*(Ck.y-Cm.y));
    float2 Bc = f2(0.5f*(Ck.x-Cm.x), 0.5f*(Ck.y+Cm.y));
    float2 B  = f2(Bc.y, -Bc.x);
    float2 wB = cmul(w, B);
    return make_float4((A.x+wB.x)*s + bds, (A.y+wB.y)*s,
                       (A.x-wB.x)*s + bds, -((A.y-wB.y)*s));
}
// unpack X via w, multiply with packed K, repack into C'[k], C'[8192-k]
static __device__ __forceinline__ void pwmul(float2 Ck, float2 Cm, float4 Kp, float2 w,
                                             float2& Dk, float2& Dm){
    float2 A  = f2(0.5f*(Ck.x+Cm.x), 0.5f*(Ck.y-Cm.y));
    float2 Bc = f2(0.5f*(Ck.x-Cm.x), 0.5f*(Ck.y+Cm.y));
    float2 B  = f2(Bc.y, -Bc.x);
    float2 wB = cmul(w, B);
    float2 Xk = f2(A.x+wB.x, A.y+wB.y);
    float2 Xm = f2(A.x-wB.x, -(A.y-wB.y));
    float2 Yk = cmul(Xk, f2(Kp.x,Kp.y));
    float2 Ym = cmul(Xm, f2(Kp.z,Kp.w));
    float2 A2 = f2(Yk.x+Ym.x, Yk.y-Ym.y);
    float2 Bt = f2(Yk.x-Ym.x, Yk.y+Ym.y);
    float2 B2 = cmulc(Bt, w);
    Dk = f2(A2.x - B2.y, A2.y + B2.x);
    Dm = f2(A2.x + B2.y, B2.x - A2.y);
}

// LDS: cv 8192 f2 | tab 512 | T1 64 | T2 64 | Kex 2 (+2 pad) = 8836 f2 = 70688 B -> 2 blocks/CU
#define SMEM_BYTES (8836 * 8)

// NOTE: arg2 is empirically CUDA-style min-BLOCKS/CU on this hipcc:
// (512,4) gave VGPR_Count=64 (32-wave budget) + 1.8 GB scratch; (512,2) -> 128-VGPR cap.
__global__ __launch_bounds__(NT, 2)
void hyena_conv(const float* __restrict__ h3g, const float* __restrict__ Wout,
                const float* __restrict__ x, const float* __restrict__ bias,
                float* __restrict__ out) {
    extern __shared__ float4 smem4[];
    float2* cv  = (float2*)smem4;       // 8192
    float2* tab = cv + 8192;            // 512: e^{-i pi p/4096}
    float2* T1  = tab + 512;            // 64:  e^{-i pi h/128}
    float2* T2  = T1 + 64;              // 64:  e^{-i pi l/8192}
    float2* Kex = T2 + 64;              // 2:   K-pack for f=2048 (lane-0 only)
    const int t = threadIdx.x;
    const int d = blockIdx.x;
    const float PI = 3.14159265358979323846f;

    { float s_,c_; sincosf((PI/4096.0f)*(float)t, &s_, &c_); tab[t] = f2(c_, -s_); }
    if (t < 64)       { float s_,c_; sincosf((PI/128.0f)*(float)t, &s_,&c_); T1[t] = f2(c_,-s_); }
    else if (t < 128) { int l=t-64; float s_,c_; sincosf((PI/8192.0f)*(float)l,&s_,&c_); T2[l] = f2(c_,-s_); }
    __syncthreads();

    const float2 wd1 = tab[t];            // pass stride 512 (stages 12..9 / 9..12)
    const float2 wd2 = tab[(t&31)<<4];    // pass stride 32  (stages 8..5 / 5..8)
    const float2 wd3 = tab[(t&1)<<8];     // pass stride 2   (stages 4..1 / 1..4)
    const int b2 = ((t>>5)<<9) | (t&31);
    const int b3 = ((t>>1)<<5) | (t&1);

    // ---- filter row k_d -> spectrum K (kept in registers), bias folded in ----
    const float dmin = -3.0701134573253941f;   // log(0.01)/1.5
    const float dmax = -15.350567286626971f;   // log(0.01)/0.3
    const float absd = fabsf(dmin + (dmax - dmin) * ((float)d * (1.0f/1023.0f)));
    const float bds = bias[d] * (1.0f/16384.0f);

    float2 r[16];
    {
        float wcol[16];
#pragma unroll
        for (int o = 0; o < 16; ++o) wcol[o] = Wout[o*1024 + d];
#pragma unroll
        for (int k = 0; k < 8; ++k) {
            int e = t + 512*k;                      // packed complex idx; samples 2e, 2e+1
            const float4* h4 = (const float4*)(h3g + (size_t)(2*e)*16);
            float a0 = 0.f, a1 = 0.f;
#pragma unroll
            for (int v4 = 0; v4 < 4; ++v4) {
                float4 q0 = h4[v4], q1 = h4[4+v4];
                a0 += q0.x*wcol[4*v4] + q0.y*wcol[4*v4+1] + q0.z*wcol[4*v4+2] + q0.w*wcol[4*v4+3];
                a1 += q1.x*wcol[4*v4] + q1.y*wcol[4*v4+1] + q1.z*wcol[4*v4+2] + q1.w*wcol[4*v4+3];
            }
            float ta = (float)(2*e)   * (1.0f/8191.0f);
            float tb = (float)(2*e+1) * (1.0f/8191.0f);
            r[k] = f2(a0 * __expf(-ta*absd), a1 * __expf(-tb*absd));
        }
    }
#pragma unroll
    for (int k = 8; k < 16; ++k) r[k] = f2(0.f, 0.f);

    dif4(r, wd1);
#pragma unroll
    for (int k = 0; k < 16; ++k) cv[swz(t + 512*k)] = r[k];
    __syncthreads();
#pragma unroll
    for (int k = 0; k < 16; ++k) r[k] = cv[swz(b2 + 32*k)];
    dif4(r, wd2);
#pragma unroll
    for (int k = 0; k < 16; ++k) cv[swz(b2 + 32*k)] = r[k];
    __syncthreads();
#pragma unroll
    for (int k = 0; k < 16; ++k) r[k] = cv[swz(b3 + 2*k)];
    dif4(r, wd3);
#pragma unroll
    for (int k = 0; k < 16; ++k) cv[swz(b3 + 2*k)] = r[k];
    __syncthreads();

    float4 Ka[4], Kb[4];
#pragma unroll
    for (int q = 0; q < 4; ++q) {
        int f = t + 512*q;
        if (f == 0) {
            float2 a0,a1; readpair(cv, 0, a0, a1);
            float2 C0 = cadd(a0,a1), C4 = csub(a0,a1);   // fwd stage 0
            const float s = 1.0f/16384.0f;
            Ka[q] = make_float4((C0.x+C0.y)*s + bds, (C0.x-C0.y)*s + bds, C4.x*s + bds, -C4.y*s);
            Kb[q] = make_float4(0.f,0.f,0.f,0.f);
        } else {
            int g = 4096 - f;
            float2 a0,a1,b0,b1;
            readpair(cv, rev13(f), a0, a1);
            readpair(cv, rev13(g), b0, b1);
            float2 Cf=cadd(a0,a1), Cf4=csub(a0,a1), Cg=cadd(b0,b1), Cg4=csub(b0,b1);
            Ka[q] = kpack(Cf, Cg4, getw(T1,T2,f), bds);
            Kb[q] = kpack(Cg, Cf4, getw(T1,T2,g), bds);
        }
    }
    if (t == 0) {
        float2 b0,b1; readpair(cv, 2, b0, b1);   // rev13(2048) = 2
        float4 K20 = kpack(cadd(b0,b1), csub(b0,b1), getw(T1,T2,2048), bds);
        Kex[0] = f2(K20.x, K20.y);
        Kex[1] = f2(K20.z, K20.w);
    }
    __syncthreads();

    // ---- batches ----
    for (int b = 0; b < 4; ++b) {
        const float2* xr = (const float2*)(x + ((size_t)b*1024 + d)*SEQ_LEN);
        float2* yr = (float2*)(out + ((size_t)b*1024 + d)*SEQ_LEN);

        // F1: global -> regs, stages 12..9, -> LDS
#pragma unroll
        for (int k = 0; k < 8; ++k) r[k] = xr[t + 512*k];
#pragma unroll
        for (int k = 8; k < 16; ++k) r[k] = f2(0.f,0.f);
        dif4(r, wd1);
#pragma unroll
        for (int k = 0; k < 16; ++k) cv[swz(t + 512*k)] = r[k];
        __syncthreads();
        // F2: stages 8..5
#pragma unroll
        for (int k = 0; k < 16; ++k) r[k] = cv[swz(b2 + 32*k)];
        dif4(r, wd2);
#pragma unroll
        for (int k = 0; k < 16; ++k) cv[swz(b2 + 32*k)] = r[k];
        __syncthreads();
        // F3: stages 4..1
#pragma unroll
        for (int k = 0; k < 16; ++k) r[k] = cv[swz(b3 + 2*k)];
        dif4(r, wd3);
#pragma unroll
        for (int k = 0; k < 16; ++k) cv[swz(b3 + 2*k)] = r[k];
        __syncthreads();

        // FUSED: fwd stage 0 + rfft-unpack * K + repack + inv stage 0
#pragma unroll
        for (int q = 0; q < 4; ++q) {
            int f = t + 512*q;
            if (f == 0) {
                float2 a0,a1; readpair(cv, 0, a0, a1);
                float2 C0 = cadd(a0,a1), C4 = csub(a0,a1);
                float R0 = C0.x + C0.y, RN = C0.x - C0.y;
                float Y0 = R0 * Ka[0].x, YN = RN * Ka[0].y;
                float2 D0 = f2(Y0+YN, Y0-YN);
                float2 Y4 = cmul(f2(C4.x,-C4.y), f2(Ka[0].z, Ka[0].w));
                float2 D4 = f2(2.f*Y4.x, -2.f*Y4.y);
                writepair(cv, 0, cadd(D0,D4), csub(D0,D4));
            } else {
                int g = 4096 - f;
                int p1 = rev13(f), p2 = rev13(g);
                float2 a0,a1,b0,b1;
                readpair(cv, p1, a0, a1);
                readpair(cv, p2, b0, b1);
                float2 Cf=cadd(a0,a1), Cf4=csub(a0,a1), Cg=cadd(b0,b1), Cg4=csub(b0,b1);
                float2 Df,Dg4,Dg,Df4;
                pwmul(Cf, Cg4, Ka[q], getw(T1,T2,f), Df, Dg4);
                pwmul(Cg, Cf4, Kb[q], getw(T1,T2,g), Dg, Df4);
                writepair(cv, p1, cadd(Df,Df4), csub(Df,Df4));
                writepair(cv, p2, cadd(Dg,Dg4), csub(Dg,Dg4));
            }
        }
        if (t == 0) {   // f = 2048 self-paired quad at positions (2,3)
            float4 K20 = make_float4(Kex[0].x, Kex[0].y, Kex[1].x, Kex[1].y);
            float2 b0,b1; readpair(cv, 2, b0, b1);
            float2 Ck=cadd(b0,b1), Cm=csub(b0,b1), Dk, Dm;
            pwmul(Ck, Cm, K20, getw(T1,T2,2048), Dk, Dm);
            writepair(cv, 2, cadd(Dk,Dm), csub(Dk,Dm));
        }
        __syncthreads();

        // I2: stages 1..4
#pragma unroll
        for (int k = 0; k < 16; ++k) r[k] = cv[swz(b3 + 2*k)];
        dit4(r, wd3);
#pragma unroll
        for (int k = 0; k < 16; ++k) cv[swz(b3 + 2*k)] = r[k];
        __syncthreads();
        // I3: stages 5..8
#pragma unroll
        for (int k = 0; k < 16; ++k) r[k] = cv[swz(b2 + 32*k)];
        dit4(r, wd2);
#pragma unroll
        for (int k = 0; k < 16; ++k) cv[swz(b2 + 32*k)] = r[k];
        __syncthreads();
        // I4: stages 9..12, write first half straight to global (bias folded into K)
#pragma unroll
        for (int k = 0; k < 16; ++k) r[k] = cv[swz(t + 512*k)];
        dit4(r, wd1);
#pragma unroll
        for (int k = 0; k < 8; ++k) yr[t + 512*k] = r[k];
        __syncthreads();
    }
}

extern "C" void kernel_launch(void* const* d_in, const int* in_sizes, int n_in,
                              void* d_out, int out_size, void* d_ws, size_t ws_size,
                              hipStream_t stream) {
    const float* x    = (const float*)d_in[0];
    const float* z    = (const float*)d_in[2];
    const float* W1   = (const float*)d_in[3];
    const float* b1   = (const float*)d_in[4];
    const float* W2   = (const float*)d_in[5];
    const float* b2   = (const float*)d_in[6];
    const float* W3   = (const float*)d_in[7];
    const float* b3   = (const float*)d_in[8];
    const float* Wout = (const float*)d_in[9];
    const float* freq = (const float*)d_in[10];
    const float* bias = (const float*)d_in[11];
    float* out = (float*)d_out;
    float* h3  = (float*)d_ws;   // 8192*16 floats = 512 KB

    hipLaunchKernelGGL(hyena_mlp, dim3(SEQ_LEN/256), dim3(256), 0, stream,
                       z, W1, b1, W2, b2, W3, b3, freq, h3);

    static bool attr_set = false;
    if (!attr_set) {
        (void)hipFuncSetAttribute((const void*)hyena_conv,
                                  hipFuncAttributeMaxDynamicSharedMemorySize,
                                  SMEM_BYTES);
        attr_set = true;
    }
    hipLaunchKernelGGL(hyena_conv, dim3(1024), dim3(NT), SMEM_BYTES, stream,
                       h3, Wout, x, bias, out);
}

// Round 5
// 644.539 us; speedup vs baseline: 1.0229x; 1.0229x over previous
//
#include <hip/hip_runtime.h>

#define NT 512
#define SEQ_LEN 8192

static __device__ __forceinline__ float2 f2(float x, float y){ return make_float2(x,y); }
static __device__ __forceinline__ float2 cadd(float2 a, float2 b){ return f2(a.x+b.x, a.y+b.y); }
static __device__ __forceinline__ float2 csub(float2 a, float2 b){ return f2(a.x-b.x, a.y-b.y); }
static __device__ __forceinline__ float2 cmul(float2 a, float2 b){ return f2(a.x*b.x-a.y*b.y, a.x*b.y+a.y*b.x); }
static __device__ __forceinline__ float2 cmulc(float2 a, float2 b){ return f2(a.x*b.x+a.y*b.y, a.y*b.x-a.x*b.y); } // a*conj(b)
static __device__ __forceinline__ float2 mul_mi(float2 a){ return f2(a.y, -a.x); }  // a * (-i)
static __device__ __forceinline__ float2 mul_pi(float2 a){ return f2(-a.y, a.x); }  // a * (+i)
static __device__ __forceinline__ int swz(int e){ return e ^ ((e>>4)&15) ^ ((e>>8)&15); }
static __device__ __forceinline__ int rev13(int v){ return (int)(__brev((unsigned)v) >> 19); }

// ---------------- MLP: h3[j][16] = sin-MLP(z[j]) ----------------
__global__ void hyena_mlp(const float* __restrict__ z,
                          const float* __restrict__ W1, const float* __restrict__ b1,
                          const float* __restrict__ W2, const float* __restrict__ b2,
                          const float* __restrict__ W3, const float* __restrict__ b3,
                          const float* __restrict__ freq,
                          float* __restrict__ h3) {
    int j = blockIdx.x * blockDim.x + threadIdx.x;
    if (j >= SEQ_LEN) return;
    float z0 = z[3*j+0], z1 = z[3*j+1], z2 = z[3*j+2];
    float ha[16], hb[16];
#pragma unroll
    for (int o = 0; o < 16; ++o) {
        float acc = b1[o] + z0*W1[o] + z1*W1[16+o] + z2*W1[32+o];
        ha[o] = sinf(freq[o] * acc);
    }
#pragma unroll
    for (int p = 0; p < 16; ++p) {
        float acc = b2[p];
#pragma unroll
        for (int o = 0; o < 16; ++o) acc += ha[o] * W2[o*16+p];
        hb[p] = sinf(freq[p] * acc);
    }
#pragma unroll
    for (int q = 0; q < 16; ++q) {
        float acc = b3[q];
#pragma unroll
        for (int o = 0; o < 16; ++o) acc += hb[o] * W3[o*16+q];
        h3[j*16+q] = sinf(freq[q] * acc);
    }
}

// ------ 4-stage (radix-16-as-radix-2^4) register butterflies, slim twiddles ------
static __device__ __forceinline__ void dif4(float2 r[16], float2 wd){
    const float2 c1 = f2(0.9238795325112867f,-0.3826834323650898f);  // e^{-i pi/8}
    const float2 c2 = f2(0.7071067811865476f,-0.7071067811865476f);  // e^{-i pi/4}
    const float2 c3 = f2(0.3826834323650898f,-0.9238795325112867f);  // e^{-i 3pi/8}
    float2 wc = cmul(wd,wd), wb = cmul(wc,wc), wa = cmul(wb,wb);
    float2 t0 = wd, t1 = cmul(wd,c1), t2 = cmul(wd,c2), t3 = cmul(wd,c3);
    float2 u0 = wc, u1 = cmul(wc,c2);
    // stage A (stride 8)
    { float2 u=r[0], v=r[8];  r[0]=cadd(u,v); r[8] =cmul(csub(u,v), t0); }
    { float2 u=r[1], v=r[9];  r[1]=cadd(u,v); r[9] =cmul(csub(u,v), t1); }
    { float2 u=r[2], v=r[10]; r[2]=cadd(u,v); r[10]=cmul(csub(u,v), t2); }
    { float2 u=r[3], v=r[11]; r[3]=cadd(u,v); r[11]=cmul(csub(u,v), t3); }
    { float2 u=r[4], v=r[12]; r[4]=cadd(u,v); r[12]=mul_mi(cmul(csub(u,v), t0)); }
    { float2 u=r[5], v=r[13]; r[5]=cadd(u,v); r[13]=mul_mi(cmul(csub(u,v), t1)); }
    { float2 u=r[6], v=r[14]; r[6]=cadd(u,v); r[14]=mul_mi(cmul(csub(u,v), t2)); }
    { float2 u=r[7], v=r[15]; r[7]=cadd(u,v); r[15]=mul_mi(cmul(csub(u,v), t3)); }
    // stage B (stride 4)
#pragma unroll
    for (int b = 0; b < 16; b += 8) {
        { float2 u=r[b+0], v=r[b+4]; r[b+0]=cadd(u,v); r[b+4]=cmul(csub(u,v), u0); }
        { float2 u=r[b+1], v=r[b+5]; r[b+1]=cadd(u,v); r[b+5]=cmul(csub(u,v), u1); }
        { float2 u=r[b+2], v=r[b+6]; r[b+2]=cadd(u,v); r[b+6]=mul_mi(cmul(csub(u,v), u0)); }
        { float2 u=r[b+3], v=r[b+7]; r[b+3]=cadd(u,v); r[b+7]=mul_mi(cmul(csub(u,v), u1)); }
    }
    // stage C (stride 2)
#pragma unroll
    for (int b = 0; b < 16; b += 4) {
        { float2 u=r[b+0], v=r[b+2]; r[b+0]=cadd(u,v); r[b+2]=cmul(csub(u,v), wb); }
        { float2 u=r[b+1], v=r[b+3]; r[b+1]=cadd(u,v); r[b+3]=mul_mi(cmul(csub(u,v), wb)); }
    }
    // stage D (stride 1)
#pragma unroll
    for (int b = 0; b < 16; b += 2) { float2 u=r[b], v=r[b+1]; r[b]=cadd(u,v); r[b+1]=cmul(csub(u,v), wa); }
}
static __device__ __forceinline__ void dit4(float2 r[16], float2 wd){
    const float2 c1 = f2(0.9238795325112867f,-0.3826834323650898f);
    const float2 c2 = f2(0.7071067811865476f,-0.7071067811865476f);
    const float2 c3 = f2(0.3826834323650898f,-0.9238795325112867f);
    float2 wc = cmul(wd,wd), wb = cmul(wc,wc), wa = cmul(wb,wb);
    float2 t0 = wd, t1 = cmul(wd,c1), t2 = cmul(wd,c2), t3 = cmul(wd,c3);
    float2 u0 = wc, u1 = cmul(wc,c2);
    // stage D' (stride 1), conj(wa)
#pragma unroll
    for (int b = 0; b < 16; b += 2) { float2 u=r[b]; float2 t=cmulc(r[b+1], wa); r[b]=cadd(u,t); r[b+1]=csub(u,t); }
    // stage C' (stride 2): conj(wb) and conj(-i wb) = +i conj(wb)
#pragma unroll
    for (int b = 0; b < 16; b += 4) {
        { float2 u=r[b+0]; float2 t=cmulc(r[b+2], wb);         r[b+0]=cadd(u,t); r[b+2]=csub(u,t); }
        { float2 u=r[b+1]; float2 t=mul_pi(cmulc(r[b+3], wb)); r[b+1]=cadd(u,t); r[b+3]=csub(u,t); }
    }
    // stage B' (stride 4)
#pragma unroll
    for (int b = 0; b < 16; b += 8) {
        { float2 u=r[b+0]; float2 t=cmulc(r[b+4], u0);         r[b+0]=cadd(u,t); r[b+4]=csub(u,t); }
        { float2 u=r[b+1]; float2 t=cmulc(r[b+5], u1);         r[b+1]=cadd(u,t); r[b+5]=csub(u,t); }
        { float2 u=r[b+2]; float2 t=mul_pi(cmulc(r[b+6], u0)); r[b+2]=cadd(u,t); r[b+6]=csub(u,t); }
        { float2 u=r[b+3]; float2 t=mul_pi(cmulc(r[b+7], u1)); r[b+3]=cadd(u,t); r[b+7]=csub(u,t); }
    }
    // stage A' (stride 8)
    { float2 u=r[0]; float2 t=cmulc(r[8],  t0);        r[0]=cadd(u,t); r[8] =csub(u,t); }
    { float2 u=r[1]; float2 t=cmulc(r[9],  t1);        r[1]=cadd(u,t); r[9] =csub(u,t); }
    { float2 u=r[2]; float2 t=cmulc(r[10], t2);        r[2]=cadd(u,t); r[10]=csub(u,t); }
    { float2 u=r[3]; float2 t=cmulc(r[11], t3);        r[3]=cadd(u,t); r[11]=csub(u,t); }
    { float2 u=r[4]; float2 t=mul_pi(cmulc(r[12], t0)); r[4]=cadd(u,t); r[12]=csub(u,t); }
    { float2 u=r[5]; float2 t=mul_pi(cmulc(r[13], t1)); r[5]=cadd(u,t); r[13]=csub(u,t); }
    { float2 u=r[6]; float2 t=mul_pi(cmulc(r[14], t2)); r[6]=cadd(u,t); r[14]=csub(u,t); }
    { float2 u=r[7]; float2 t=mul_pi(cmulc(r[15], t3)); r[7]=cadd(u,t); r[15]=csub(u,t); }
}

// aligned pair access (positions p even; swz may flip parity, so select)
static __device__ __forceinline__ void readpair(const float2* cv, int p, float2& e0, float2& e1){
    int sp = swz(p);
    float4 q = *(const float4*)&cv[sp & ~1];
    float2 lo = f2(q.x,q.y), hi = f2(q.z,q.w);
    if (sp & 1) { e0 = hi; e1 = lo; } else { e0 = lo; e1 = hi; }
}
static __device__ __forceinline__ void writepair(float2* cv, int p, float2 e0, float2 e1){
    int sp = swz(p);
    float4 q;
    if (sp & 1) q = make_float4(e1.x,e1.y,e0.x,e0.y);
    else        q = make_float4(e0.x,e0.y,e1.x,e1.y);
    *(float4*)&cv[sp & ~1] = q;
}

static __device__ __forceinline__ float2 getw(const float2* T1, const float2* T2, int k){
    return cmul(T1[k>>6], T2[k&63]);   // e^{-i pi k / 8192}
}
// rfft unpack K[k], K[8192-k] packed as float4 (scaled by 1/16384, +bias*s on real parts)
static __device__ __forceinline__ float4 kpack(float2 Ck, float2 Cm, float2 w, float bds){
    const float s = 1.0f/16384.0f;
    float2 A  = f2(0.5f*(Ck.x+Cm.x), 0.5f*(Ck.y-Cm.y));
    float2 Bc = f2(0.5f*(Ck.x-Cm.x), 0.5f*(Ck.y+Cm.y));
    float2 B  = f2(Bc.y, -Bc.x);
    float2 wB = cmul(w, B);
    return make_float4((A.x+wB.x)*s + bds, (A.y+wB.y)*s,
                       (A.x-wB.x)*s + bds, -((A.y-wB.y)*s));
}
// unpack X via w, multiply with packed K, repack into C'[k], C'[8192-k]
static __device__ __forceinline__ void pwmul(float2 Ck, float2 Cm, float4 Kp, float2 w,
                                             float2& Dk, float2& Dm){
    float2 A  = f2(0.5f*(Ck.x+Cm.x), 0.5f*(Ck.y-Cm.y));
    float2 Bc = f2(0.5f*(Ck.x-Cm.x), 0.5f*(Ck.y+Cm.y));
    float2 B  = f2(Bc.y, -Bc.x);
    float2 wB = cmul(w, B);
    float2 Xk = f2(A.x+wB.x, A.y+wB.y);
    float2 Xm = f2(A.x-wB.x, -(A.y-wB.y));
    float2 Yk = cmul(Xk, f2(Kp.x,Kp.y));
    float2 Ym = cmul(Xm, f2(Kp.z,Kp.w));
    float2 A2 = f2(Yk.x+Ym.x, Yk.y-Ym.y);
    float2 Bt = f2(Yk.x-Ym.x, Yk.y+Ym.y);
    float2 B2 = cmulc(Bt, w);
    Dk = f2(A2.x - B2.y, A2.y + B2.x);
    Dm = f2(A2.x + B2.y, B2.x - A2.y);
}

// LDS: cv 8192 f2 | tab 512 | T1 64 | T2 64 | Kex 2 (+2 pad) = 8836 f2 = 70688 B
#define SMEM_BYTES (8836 * 8)

// VGPR-cap map on this hipcc (measured): (512,4)->64, (512,2)->128 -> both spilled.
// Occupancy was ~1 block/CU (23%) even at the 128 cap, so the cap bought nothing.
// (512,1) -> 256-VGPR cap: the ~110-reg working set fits, zero scratch, same residency.
__global__ __launch_bounds__(NT, 1)
void hyena_conv(const float* __restrict__ h3g, const float* __restrict__ Wout,
                const float* __restrict__ x, const float* __restrict__ bias,
                float* __restrict__ out) {
    extern __shared__ float4 smem4[];
    float2* cv  = (float2*)smem4;       // 8192
    float2* tab = cv + 8192;            // 512: e^{-i pi p/4096}
    float2* T1  = tab + 512;            // 64:  e^{-i pi h/128}
    float2* T2  = T1 + 64;              // 64:  e^{-i pi l/8192}
    float2* Kex = T2 + 64;              // 2:   K-pack for f=2048 (lane-0 only)
    const int t = threadIdx.x;
    const int d = blockIdx.x;
    const float PI = 3.14159265358979323846f;

    { float s_,c_; sincosf((PI/4096.0f)*(float)t, &s_, &c_); tab[t] = f2(c_, -s_); }
    if (t < 64)       { float s_,c_; sincosf((PI/128.0f)*(float)t, &s_,&c_); T1[t] = f2(c_,-s_); }
    else if (t < 128) { int l=t-64; float s_,c_; sincosf((PI/8192.0f)*(float)l,&s_,&c_); T2[l] = f2(c_,-s_); }
    __syncthreads();

    const float2 wd1 = tab[t];            // pass stride 512 (stages 12..9 / 9..12)
    const float2 wd2 = tab[(t&31)<<4];    // pass stride 32  (stages 8..5 / 5..8)
    const float2 wd3 = tab[(t&1)<<8];     // pass stride 2   (stages 4..1 / 1..4)
    const int b2 = ((t>>5)<<9) | (t&31);
    const int b3 = ((t>>1)<<5) | (t&1);

    // ---- filter row k_d -> spectrum K (kept in registers), bias folded in ----
    const float dmin = -3.0701134573253941f;   // log(0.01)/1.5
    const float dmax = -15.350567286626971f;   // log(0.01)/0.3
    const float absd = fabsf(dmin + (dmax - dmin) * ((float)d * (1.0f/1023.0f)));
    const float bds = bias[d] * (1.0f/16384.0f);

    float2 r[16];
    {
        float wcol[16];
#pragma unroll
        for (int o = 0; o < 16; ++o) wcol[o] = Wout[o*1024 + d];
#pragma unroll
        for (int k = 0; k < 8; ++k) {
            int e = t + 512*k;                      // packed complex idx; samples 2e, 2e+1
            const float4* h4 = (const float4*)(h3g + (size_t)(2*e)*16);
            float a0 = 0.f, a1 = 0.f;
#pragma unroll
            for (int v4 = 0; v4 < 4; ++v4) {
                float4 q0 = h4[v4], q1 = h4[4+v4];
                a0 += q0.x*wcol[4*v4] + q0.y*wcol[4*v4+1] + q0.z*wcol[4*v4+2] + q0.w*wcol[4*v4+3];
                a1 += q1.x*wcol[4*v4] + q1.y*wcol[4*v4+1] + q1.z*wcol[4*v4+2] + q1.w*wcol[4*v4+3];
            }
            float ta = (float)(2*e)   * (1.0f/8191.0f);
            float tb = (float)(2*e+1) * (1.0f/8191.0f);
            r[k] = f2(a0 * __expf(-ta*absd), a1 * __expf(-tb*absd));
        }
    }
#pragma unroll
    for (int k = 8; k < 16; ++k) r[k] = f2(0.f, 0.f);

    dif4(r, wd1);
#pragma unroll
    for (int k = 0; k < 16; ++k) cv[swz(t + 512*k)] = r[k];
    __syncthreads();
#pragma unroll
    for (int k = 0; k < 16; ++k) r[k] = cv[swz(b2 + 32*k)];
    dif4(r, wd2);
#pragma unroll
    for (int k = 0; k < 16; ++k) cv[swz(b2 + 32*k)] = r[k];
    __syncthreads();
#pragma unroll
    for (int k = 0; k < 16; ++k) r[k] = cv[swz(b3 + 2*k)];
    dif4(r, wd3);
#pragma unroll
    for (int k = 0; k < 16; ++k) cv[swz(b3 + 2*k)] = r[k];
    __syncthreads();

    float4 Ka[4], Kb[4];
#pragma unroll
    for (int q = 0; q < 4; ++q) {
        int f = t + 512*q;
        if (f == 0) {
            float2 a0,a1; readpair(cv, 0, a0, a1);
            float2 C0 = cadd(a0,a1), C4 = csub(a0,a1);   // fwd stage 0
            const float s = 1.0f/16384.0f;
            Ka[q] = make_float4((C0.x+C0.y)*s + bds, (C0.x-C0.y)*s + bds, C4.x*s + bds, -C4.y*s);
            Kb[q] = make_float4(0.f,0.f,0.f,0.f);
        } else {
            int g = 4096 - f;
            float2 a0,a1,b0,b1;
            readpair(cv, rev13(f), a0, a1);
            readpair(cv, rev13(g), b0, b1);
            float2 Cf=cadd(a0,a1), Cf4=csub(a0,a1), Cg=cadd(b0,b1), Cg4=csub(b0,b1);
            Ka[q] = kpack(Cf, Cg4, getw(T1,T2,f), bds);
            Kb[q] = kpack(Cg, Cf4, getw(T1,T2,g), bds);
        }
    }
    if (t == 0) {
        float2 b0,b1; readpair(cv, 2, b0, b1);   // rev13(2048) = 2
        float4 K20 = kpack(cadd(b0,b1), csub(b0,b1), getw(T1,T2,2048), bds);
        Kex[0] = f2(K20.x, K20.y);
        Kex[1] = f2(K20.z, K20.w);
    }
    __syncthreads();

    // ---- batches ----
    for (int b = 0; b < 4; ++b) {
        const float2* xr = (const float2*)(x + ((size_t)b*1024 + d)*SEQ_LEN);
        float2* yr = (float2*)(out + ((size_t)b*1024 + d)*SEQ_LEN);

        // F1: global -> regs, stages 12..9, -> LDS
#pragma unroll
        for (int k = 0; k < 8; ++k) r[k] = xr[t + 512*k];
#pragma unroll
        for (int k = 8; k < 16; ++k) r[k] = f2(0.f,0.f);
        dif4(r, wd1);
#pragma unroll
        for (int k = 0; k < 16; ++k) cv[swz(t + 512*k)] = r[k];
        __syncthreads();
        // F2: stages 8..5
#pragma unroll
        for (int k = 0; k < 16; ++k) r[k] = cv[swz(b2 + 32*k)];
        dif4(r, wd2);
#pragma unroll
        for (int k = 0; k < 16; ++k) cv[swz(b2 + 32*k)] = r[k];
        __syncthreads();
        // F3: stages 4..1
#pragma unroll
        for (int k = 0; k < 16; ++k) r[k] = cv[swz(b3 + 2*k)];
        dif4(r, wd3);
#pragma unroll
        for (int k = 0; k < 16; ++k) cv[swz(b3 + 2*k)] = r[k];
        __syncthreads();

        // FUSED: fwd stage 0 + rfft-unpack * K + repack + inv stage 0
#pragma unroll
        for (int q = 0; q < 4; ++q) {
            int f = t + 512*q;
            if (f == 0) {
                float2 a0,a1; readpair(cv, 0, a0, a1);
                float2 C0 = cadd(a0,a1), C4 = csub(a0,a1);
                float R0 = C0.x + C0.y, RN = C0.x - C0.y;
                float Y0 = R0 * Ka[0].x, YN = RN * Ka[0].y;
                float2 D0 = f2(Y0+YN, Y0-YN);
                float2 Y4 = cmul(f2(C4.x,-C4.y), f2(Ka[0].z, Ka[0].w));
                float2 D4 = f2(2.f*Y4.x, -2.f*Y4.y);
                writepair(cv, 0, cadd(D0,D4), csub(D0,D4));
            } else {
                int g = 4096 - f;
                int p1 = rev13(f), p2 = rev13(g);
                float2 a0,a1,b0,b1;
                readpair(cv, p1, a0, a1);
                readpair(cv, p2, b0, b1);
                float2 Cf=cadd(a0,a1), Cf4=csub(a0,a1), Cg=cadd(b0,b1), Cg4=csub(b0,b1);
                float2 Df,Dg4,Dg,Df4;
                pwmul(Cf, Cg4, Ka[q], getw(T1,T2,f), Df, Dg4);
                pwmul(Cg, Cf4, Kb[q], getw(T1,T2,g), Dg, Df4);
                writepair(cv, p1, cadd(Df,Df4), csub(Df,Df4));
                writepair(cv, p2, cadd(Dg,Dg4), csub(Dg,Dg4));
            }
        }
        if (t == 0) {   // f = 2048 self-paired quad at positions (2,3)
            float4 K20 = make_float4(Kex[0].x, Kex[0].y, Kex[1].x, Kex[1].y);
            float2 b0,b1; readpair(cv, 2, b0, b1);
            float2 Ck=cadd(b0,b1), Cm=csub(b0,b1), Dk, Dm;
            pwmul(Ck, Cm, K20, getw(T1,T2,2048), Dk, Dm);
            writepair(cv, 2, cadd(Dk,Dm), csub(Dk,Dm));
        }
        __syncthreads();

        // I2: stages 1..4
#pragma unroll
        for (int k = 0; k < 16; ++k) r[k] = cv[swz(b3 + 2*k)];
        dit4(r, wd3);
#pragma unroll
        for (int k = 0; k < 16; ++k) cv[swz(b3 + 2*k)] = r[k];
        __syncthreads();
        // I3: stages 5..8
#pragma unroll
        for (int k = 0; k < 16; ++k) r[k] = cv[swz(b2 + 32*k)];
        dit4(r, wd2);
#pragma unroll
        for (int k = 0; k < 16; ++k) cv[swz(b2 + 32*k)] = r[k];
        __syncthreads();
        // I4: stages 9..12, write first half straight to global (bias folded into K)
#pragma unroll
        for (int k = 0; k < 16; ++k) r[k] = cv[swz(t + 512*k)];
        dit4(r, wd1);
#pragma unroll
        for (int k = 0; k < 8; ++k) yr[t + 512*k] = r[k];
        __syncthreads();
    }
}

extern "C" void kernel_launch(void* const* d_in, const int* in_sizes, int n_in,
                              void* d_out, int out_size, void* d_ws, size_t ws_size,
                              hipStream_t stream) {
    const float* x    = (const float*)d_in[0];
    const float* z    = (const float*)d_in[2];
    const float* W1   = (const float*)d_in[3];
    const float* b1   = (const float*)d_in[4];
    const float* W2   = (const float*)d_in[5];
    const float* b2   = (const float*)d_in[6];
    const float* W3   = (const float*)d_in[7];
    const float* b3   = (const float*)d_in[8];
    const float* Wout = (const float*)d_in[9];
    const float* freq = (const float*)d_in[10];
    const float* bias = (const float*)d_in[11];
    float* out = (float*)d_out;
    float* h3  = (float*)d_ws;   // 8192*16 floats = 512 KB

    hipLaunchKernelGGL(hyena_mlp, dim3(SEQ_LEN/256), dim3(256), 0, stream,
                       z, W1, b1, W2, b2, W3, b3, freq, h3);

    static bool attr_set = false;
    if (!attr_set) {
        (void)hipFuncSetAttribute((const void*)hyena_conv,
                                  hipFuncAttributeMaxDynamicSharedMemorySize,
                                  SMEM_BYTES);
        attr_set = true;
    }
    hipLaunchKernelGGL(hyena_conv, dim3(1024), dim3(NT), SMEM_BYTES, stream,
                       h3, Wout, x, bias, out);
}

// Round 6
// 558.948 us; speedup vs baseline: 1.1795x; 1.1531x over previous
//
#include <hip/hip_runtime.h>

#define NT 512
#define SEQ_LEN 8192

static __device__ __forceinline__ float2 f2(float x, float y){ return make_float2(x,y); }
static __device__ __forceinline__ float2 cadd(float2 a, float2 b){ return f2(a.x+b.x, a.y+b.y); }
static __device__ __forceinline__ float2 csub(float2 a, float2 b){ return f2(a.x-b.x, a.y-b.y); }
static __device__ __forceinline__ float2 cmul(float2 a, float2 b){ return f2(a.x*b.x-a.y*b.y, a.x*b.y+a.y*b.x); }
static __device__ __forceinline__ float2 cmulc(float2 a, float2 b){ return f2(a.x*b.x+a.y*b.y, a.y*b.x-a.x*b.y); } // a*conj(b)
static __device__ __forceinline__ float2 mul_mi(float2 a){ return f2(a.y, -a.x); }  // a * (-i)
static __device__ __forceinline__ float2 mul_pi(float2 a){ return f2(-a.y, a.x); }  // a * (+i)
static __device__ __forceinline__ int swz(int e){ return e ^ ((e>>4)&15) ^ ((e>>8)&15); }
static __device__ __forceinline__ int rev13(int v){ return (int)(__brev((unsigned)v) >> 19); }

// ---------------- MLP: h3[j][16] = sin-MLP(z[j]) ----------------
__global__ void hyena_mlp(const float* __restrict__ z,
                          const float* __restrict__ W1, const float* __restrict__ b1,
                          const float* __restrict__ W2, const float* __restrict__ b2,
                          const float* __restrict__ W3, const float* __restrict__ b3,
                          const float* __restrict__ freq,
                          float* __restrict__ h3) {
    int j = blockIdx.x * blockDim.x + threadIdx.x;
    if (j >= SEQ_LEN) return;
    float z0 = z[3*j+0], z1 = z[3*j+1], z2 = z[3*j+2];
    float ha[16], hb[16];
#pragma unroll
    for (int o = 0; o < 16; ++o) {
        float acc = b1[o] + z0*W1[o] + z1*W1[16+o] + z2*W1[32+o];
        ha[o] = sinf(freq[o] * acc);
    }
#pragma unroll
    for (int p = 0; p < 16; ++p) {
        float acc = b2[p];
#pragma unroll
        for (int o = 0; o < 16; ++o) acc += ha[o] * W2[o*16+p];
        hb[p] = sinf(freq[p] * acc);
    }
#pragma unroll
    for (int q = 0; q < 16; ++q) {
        float acc = b3[q];
#pragma unroll
        for (int o = 0; o < 16; ++o) acc += hb[o] * W3[o*16+q];
        h3[j*16+q] = sinf(freq[q] * acc);
    }
}

// ------ 4-stage (radix-16-as-radix-2^4) register butterflies, slim twiddles ------
static __device__ __forceinline__ void dif4(float2 r[16], float2 wd){
    const float2 c1 = f2(0.9238795325112867f,-0.3826834323650898f);  // e^{-i pi/8}
    const float2 c2 = f2(0.7071067811865476f,-0.7071067811865476f);  // e^{-i pi/4}
    const float2 c3 = f2(0.3826834323650898f,-0.9238795325112867f);  // e^{-i 3pi/8}
    float2 wc = cmul(wd,wd), wb = cmul(wc,wc), wa = cmul(wb,wb);
    float2 t0 = wd, t1 = cmul(wd,c1), t2 = cmul(wd,c2), t3 = cmul(wd,c3);
    float2 u0 = wc, u1 = cmul(wc,c2);
    // stage A (stride 8)
    { float2 u=r[0], v=r[8];  r[0]=cadd(u,v); r[8] =cmul(csub(u,v), t0); }
    { float2 u=r[1], v=r[9];  r[1]=cadd(u,v); r[9] =cmul(csub(u,v), t1); }
    { float2 u=r[2], v=r[10]; r[2]=cadd(u,v); r[10]=cmul(csub(u,v), t2); }
    { float2 u=r[3], v=r[11]; r[3]=cadd(u,v); r[11]=cmul(csub(u,v), t3); }
    { float2 u=r[4], v=r[12]; r[4]=cadd(u,v); r[12]=mul_mi(cmul(csub(u,v), t0)); }
    { float2 u=r[5], v=r[13]; r[5]=cadd(u,v); r[13]=mul_mi(cmul(csub(u,v), t1)); }
    { float2 u=r[6], v=r[14]; r[6]=cadd(u,v); r[14]=mul_mi(cmul(csub(u,v), t2)); }
    { float2 u=r[7], v=r[15]; r[7]=cadd(u,v); r[15]=mul_mi(cmul(csub(u,v), t3)); }
    // stage B (stride 4)
#pragma unroll
    for (int b = 0; b < 16; b += 8) {
        { float2 u=r[b+0], v=r[b+4]; r[b+0]=cadd(u,v); r[b+4]=cmul(csub(u,v), u0); }
        { float2 u=r[b+1], v=r[b+5]; r[b+1]=cadd(u,v); r[b+5]=cmul(csub(u,v), u1); }
        { float2 u=r[b+2], v=r[b+6]; r[b+2]=cadd(u,v); r[b+6]=mul_mi(cmul(csub(u,v), u0)); }
        { float2 u=r[b+3], v=r[b+7]; r[b+3]=cadd(u,v); r[b+7]=mul_mi(cmul(csub(u,v), u1)); }
    }
    // stage C (stride 2)
#pragma unroll
    for (int b = 0; b < 16; b += 4) {
        { float2 u=r[b+0], v=r[b+2]; r[b+0]=cadd(u,v); r[b+2]=cmul(csub(u,v), wb); }
        { float2 u=r[b+1], v=r[b+3]; r[b+1]=cadd(u,v); r[b+3]=mul_mi(cmul(csub(u,v), wb)); }
    }
    // stage D (stride 1)
#pragma unroll
    for (int b = 0; b < 16; b += 2) { float2 u=r[b], v=r[b+1]; r[b]=cadd(u,v); r[b+1]=cmul(csub(u,v), wa); }
}
static __device__ __forceinline__ void dit4(float2 r[16], float2 wd){
    const float2 c1 = f2(0.9238795325112867f,-0.3826834323650898f);
    const float2 c2 = f2(0.7071067811865476f,-0.7071067811865476f);
    const float2 c3 = f2(0.3826834323650898f,-0.9238795325112867f);
    float2 wc = cmul(wd,wd), wb = cmul(wc,wc), wa = cmul(wb,wb);
    float2 t0 = wd, t1 = cmul(wd,c1), t2 = cmul(wd,c2), t3 = cmul(wd,c3);
    float2 u0 = wc, u1 = cmul(wc,c2);
    // stage D' (stride 1), conj(wa)
#pragma unroll
    for (int b = 0; b < 16; b += 2) { float2 u=r[b]; float2 t=cmulc(r[b+1], wa); r[b]=cadd(u,t); r[b+1]=csub(u,t); }
    // stage C' (stride 2): conj(wb) and conj(-i wb) = +i conj(wb)
#pragma unroll
    for (int b = 0; b < 16; b += 4) {
        { float2 u=r[b+0]; float2 t=cmulc(r[b+2], wb);         r[b+0]=cadd(u,t); r[b+2]=csub(u,t); }
        { float2 u=r[b+1]; float2 t=mul_pi(cmulc(r[b+3], wb)); r[b+1]=cadd(u,t); r[b+3]=csub(u,t); }
    }
    // stage B' (stride 4)
#pragma unroll
    for (int b = 0; b < 16; b += 8) {
        { float2 u=r[b+0]; float2 t=cmulc(r[b+4], u0);         r[b+0]=cadd(u,t); r[b+4]=csub(u,t); }
        { float2 u=r[b+1]; float2 t=cmulc(r[b+5], u1);         r[b+1]=cadd(u,t); r[b+5]=csub(u,t); }
        { float2 u=r[b+2]; float2 t=mul_pi(cmulc(r[b+6], u0)); r[b+2]=cadd(u,t); r[b+6]=csub(u,t); }
        { float2 u=r[b+3]; float2 t=mul_pi(cmulc(r[b+7], u1)); r[b+3]=cadd(u,t); r[b+7]=csub(u,t); }
    }
    // stage A' (stride 8)
    { float2 u=r[0]; float2 t=cmulc(r[8],  t0);        r[0]=cadd(u,t); r[8] =csub(u,t); }
    { float2 u=r[1]; float2 t=cmulc(r[9],  t1);        r[1]=cadd(u,t); r[9] =csub(u,t); }
    { float2 u=r[2]; float2 t=cmulc(r[10], t2);        r[2]=cadd(u,t); r[10]=csub(u,t); }
    { float2 u=r[3]; float2 t=cmulc(r[11], t3);        r[3]=cadd(u,t); r[11]=csub(u,t); }
    { float2 u=r[4]; float2 t=mul_pi(cmulc(r[12], t0)); r[4]=cadd(u,t); r[12]=csub(u,t); }
    { float2 u=r[5]; float2 t=mul_pi(cmulc(r[13], t1)); r[5]=cadd(u,t); r[13]=csub(u,t); }
    { float2 u=r[6]; float2 t=mul_pi(cmulc(r[14], t2)); r[6]=cadd(u,t); r[14]=csub(u,t); }
    { float2 u=r[7]; float2 t=mul_pi(cmulc(r[15], t3)); r[7]=cadd(u,t); r[15]=csub(u,t); }
}

// aligned pair access (positions p even; swz may flip parity, so select)
static __device__ __forceinline__ void readpair(const float2* cv, int p, float2& e0, float2& e1){
    int sp = swz(p);
    float4 q = *(const float4*)&cv[sp & ~1];
    float2 lo = f2(q.x,q.y), hi = f2(q.z,q.w);
    if (sp & 1) { e0 = hi; e1 = lo; } else { e0 = lo; e1 = hi; }
}
static __device__ __forceinline__ void writepair(float2* cv, int p, float2 e0, float2 e1){
    int sp = swz(p);
    float4 q;
    if (sp & 1) q = make_float4(e1.x,e1.y,e0.x,e0.y);
    else        q = make_float4(e0.x,e0.y,e1.x,e1.y);
    *(float4*)&cv[sp & ~1] = q;
}

static __device__ __forceinline__ float2 getw(const float2* T1, const float2* T2, int k){
    return cmul(T1[k>>6], T2[k&63]);   // e^{-i pi k / 8192}
}
// rfft unpack K[k], K[8192-k] packed as float4 (scaled by 1/16384, +bias*s on real parts)
static __device__ __forceinline__ float4 kpack(float2 Ck, float2 Cm, float2 w, float bds){
    const float s = 1.0f/16384.0f;
    float2 A  = f2(0.5f*(Ck.x+Cm.x), 0.5f*(Ck.y-Cm.y));
    float2 Bc = f2(0.5f*(Ck.x-Cm.x), 0.5f*(Ck.y+Cm.y));
    float2 B  = f2(Bc.y, -Bc.x);
    float2 wB = cmul(w, B);
    return make_float4((A.x+wB.x)*s + bds, (A.y+wB.y)*s,
                       (A.x-wB.x)*s + bds, -((A.y-wB.y)*s));
}
// unpack X via w, multiply with packed K, repack into C'[k], C'[8192-k]
static __device__ __forceinline__ void pwmul(float2 Ck, float2 Cm, float4 Kp, float2 w,
                                             float2& Dk, float2& Dm){
    float2 A  = f2(0.5f*(Ck.x+Cm.x), 0.5f*(Ck.y-Cm.y));
    float2 Bc = f2(0.5f*(Ck.x-Cm.x), 0.5f*(Ck.y+Cm.y));
    float2 B  = f2(Bc.y, -Bc.x);
    float2 wB = cmul(w, B);
    float2 Xk = f2(A.x+wB.x, A.y+wB.y);
    float2 Xm = f2(A.x-wB.x, -(A.y-wB.y));
    float2 Yk = cmul(Xk, f2(Kp.x,Kp.y));
    float2 Ym = cmul(Xm, f2(Kp.z,Kp.w));
    float2 A2 = f2(Yk.x+Ym.x, Yk.y-Ym.y);
    float2 Bt = f2(Yk.x-Ym.x, Yk.y+Ym.y);
    float2 B2 = cmulc(Bt, w);
    Dk = f2(A2.x - B2.y, A2.y + B2.x);
    Dm = f2(A2.x + B2.y, B2.x - A2.y);
}

// LDS layout (float2 units):
//   cv 8192 | tab 512 | T1 64 | T2 64 | Kex 2 | pad 2 | KA 4096 (2048 f4) | KB 4096
// = 17028 f2 = 136224 B  -> 1 block/CU (which is all we ever got anyway).
// Moving the K spectrum (was Ka[4]/Kb[4] = 32 VGPRs held across the whole batch
// loop) into LDS drops peak register pressure to ~80-90 -> no spill even at a
// 128-VGPR cap. Rounds 2-5 all spilled 0.5-1.8 GB of scratch because the
// allocator caps VGPRs at the LDS-implied occupancy and pressure exceeded it.
#define SMEM_BYTES (17028 * 8)

__global__ __launch_bounds__(NT, 1)
void hyena_conv(const float* __restrict__ h3g, const float* __restrict__ Wout,
                const float* __restrict__ x, const float* __restrict__ bias,
                float* __restrict__ out) {
    extern __shared__ float2 smem[];
    float2* cv  = smem;                 // 8192
    float2* tab = cv + 8192;            // 512: e^{-i pi p/4096}
    float2* T1  = tab + 512;            // 64:  e^{-i pi h/128}
    float2* T2  = T1 + 64;              // 64:  e^{-i pi l/8192}
    float2* Kex = T2 + 64;              // 2:   K-pack for f=2048 (lane-0 only)
    float4* KA  = (float4*)(Kex + 4);   // 2048 f4, byte off 70688 (16B-aligned)
    float4* KB  = KA + 2048;            // 2048 f4
    const int t = threadIdx.x;
    const int d = blockIdx.x;
    const float PI = 3.14159265358979323846f;

    { float s_,c_; sincosf((PI/4096.0f)*(float)t, &s_, &c_); tab[t] = f2(c_, -s_); }
    if (t < 64)       { float s_,c_; sincosf((PI/128.0f)*(float)t, &s_,&c_); T1[t] = f2(c_,-s_); }
    else if (t < 128) { int l=t-64; float s_,c_; sincosf((PI/8192.0f)*(float)l,&s_,&c_); T2[l] = f2(c_,-s_); }
    __syncthreads();

    const float2 wd1 = tab[t];            // pass stride 512 (stages 12..9 / 9..12)
    const float2 wd2 = tab[(t&31)<<4];    // pass stride 32  (stages 8..5 / 5..8)
    const float2 wd3 = tab[(t&1)<<8];     // pass stride 2   (stages 4..1 / 1..4)
    const int b2 = ((t>>5)<<9) | (t&31);
    const int b3 = ((t>>1)<<5) | (t&1);

    // ---- filter row k_d -> spectrum K (stored to LDS), bias folded in ----
    const float dmin = -3.0701134573253941f;   // log(0.01)/1.5
    const float dmax = -15.350567286626971f;   // log(0.01)/0.3
    const float absd = fabsf(dmin + (dmax - dmin) * ((float)d * (1.0f/1023.0f)));
    const float bds = bias[d] * (1.0f/16384.0f);

    float2 r[16];
    {
        float wcol[16];
#pragma unroll
        for (int o = 0; o < 16; ++o) wcol[o] = Wout[o*1024 + d];
#pragma unroll
        for (int k = 0; k < 8; ++k) {
            int e = t + 512*k;                      // packed complex idx; samples 2e, 2e+1
            const float4* h4 = (const float4*)(h3g + (size_t)(2*e)*16);
            float a0 = 0.f, a1 = 0.f;
#pragma unroll
            for (int v4 = 0; v4 < 4; ++v4) {
                float4 q0 = h4[v4], q1 = h4[4+v4];
                a0 += q0.x*wcol[4*v4] + q0.y*wcol[4*v4+1] + q0.z*wcol[4*v4+2] + q0.w*wcol[4*v4+3];
                a1 += q1.x*wcol[4*v4] + q1.y*wcol[4*v4+1] + q1.z*wcol[4*v4+2] + q1.w*wcol[4*v4+3];
            }
            float ta = (float)(2*e)   * (1.0f/8191.0f);
            float tb = (float)(2*e+1) * (1.0f/8191.0f);
            r[k] = f2(a0 * __expf(-ta*absd), a1 * __expf(-tb*absd));
        }
    }
#pragma unroll
    for (int k = 8; k < 16; ++k) r[k] = f2(0.f, 0.f);

    dif4(r, wd1);
#pragma unroll
    for (int k = 0; k < 16; ++k) cv[swz(t + 512*k)] = r[k];
    __syncthreads();
#pragma unroll
    for (int k = 0; k < 16; ++k) r[k] = cv[swz(b2 + 32*k)];
    dif4(r, wd2);
#pragma unroll
    for (int k = 0; k < 16; ++k) cv[swz(b2 + 32*k)] = r[k];
    __syncthreads();
#pragma unroll
    for (int k = 0; k < 16; ++k) r[k] = cv[swz(b3 + 2*k)];
    dif4(r, wd3);
#pragma unroll
    for (int k = 0; k < 16; ++k) cv[swz(b3 + 2*k)] = r[k];
    __syncthreads();

    // unpack rfft(K) and park the packed spectrum in LDS (not registers)
#pragma unroll
    for (int q = 0; q < 4; ++q) {
        int f = t + 512*q;
        if (f == 0) {
            float2 a0,a1; readpair(cv, 0, a0, a1);
            float2 C0 = cadd(a0,a1), C4 = csub(a0,a1);   // fwd stage 0
            const float s = 1.0f/16384.0f;
            KA[0] = make_float4((C0.x+C0.y)*s + bds, (C0.x-C0.y)*s + bds, C4.x*s + bds, -C4.y*s);
            KB[0] = make_float4(0.f,0.f,0.f,0.f);
        } else {
            int g = 4096 - f;
            float2 a0,a1,b0,b1;
            readpair(cv, rev13(f), a0, a1);
            readpair(cv, rev13(g), b0, b1);
            float2 Cf=cadd(a0,a1), Cf4=csub(a0,a1), Cg=cadd(b0,b1), Cg4=csub(b0,b1);
            KA[q*NT + t] = kpack(Cf, Cg4, getw(T1,T2,f), bds);
            KB[q*NT + t] = kpack(Cg, Cf4, getw(T1,T2,g), bds);
        }
    }
    if (t == 0) {
        float2 b0,b1; readpair(cv, 2, b0, b1);   // rev13(2048) = 2
        float4 K20 = kpack(cadd(b0,b1), csub(b0,b1), getw(T1,T2,2048), bds);
        Kex[0] = f2(K20.x, K20.y);
        Kex[1] = f2(K20.z, K20.w);
    }
    __syncthreads();

    // ---- batches ----
    for (int b = 0; b < 4; ++b) {
        const float2* xr = (const float2*)(x + ((size_t)b*1024 + d)*SEQ_LEN);
        float2* yr = (float2*)(out + ((size_t)b*1024 + d)*SEQ_LEN);

        // F1: global -> regs, stages 12..9, -> LDS
#pragma unroll
        for (int k = 0; k < 8; ++k) r[k] = xr[t + 512*k];
#pragma unroll
        for (int k = 8; k < 16; ++k) r[k] = f2(0.f,0.f);
        dif4(r, wd1);
#pragma unroll
        for (int k = 0; k < 16; ++k) cv[swz(t + 512*k)] = r[k];
        __syncthreads();
        // F2: stages 8..5
#pragma unroll
        for (int k = 0; k < 16; ++k) r[k] = cv[swz(b2 + 32*k)];
        dif4(r, wd2);
#pragma unroll
        for (int k = 0; k < 16; ++k) cv[swz(b2 + 32*k)] = r[k];
        __syncthreads();
        // F3: stages 4..1
#pragma unroll
        for (int k = 0; k < 16; ++k) r[k] = cv[swz(b3 + 2*k)];
        dif4(r, wd3);
#pragma unroll
        for (int k = 0; k < 16; ++k) cv[swz(b3 + 2*k)] = r[k];
        __syncthreads();

        // FUSED: fwd stage 0 + rfft-unpack * K + repack + inv stage 0
#pragma unroll
        for (int q = 0; q < 4; ++q) {
            int f = t + 512*q;
            float4 Kpa = KA[q*NT + t];
            if (f == 0) {
                float2 a0,a1; readpair(cv, 0, a0, a1);
                float2 C0 = cadd(a0,a1), C4 = csub(a0,a1);
                float R0 = C0.x + C0.y, RN = C0.x - C0.y;
                float Y0 = R0 * Kpa.x, YN = RN * Kpa.y;
                float2 D0 = f2(Y0+YN, Y0-YN);
                float2 Y4 = cmul(f2(C4.x,-C4.y), f2(Kpa.z, Kpa.w));
                float2 D4 = f2(2.f*Y4.x, -2.f*Y4.y);
                writepair(cv, 0, cadd(D0,D4), csub(D0,D4));
            } else {
                float4 Kpb = KB[q*NT + t];
                int g = 4096 - f;
                int p1 = rev13(f), p2 = rev13(g);
                float2 a0,a1,b0,b1;
                readpair(cv, p1, a0, a1);
                readpair(cv, p2, b0, b1);
                float2 Cf=cadd(a0,a1), Cf4=csub(a0,a1), Cg=cadd(b0,b1), Cg4=csub(b0,b1);
                float2 Df,Dg4,Dg,Df4;
                pwmul(Cf, Cg4, Kpa, getw(T1,T2,f), Df, Dg4);
                pwmul(Cg, Cf4, Kpb, getw(T1,T2,g), Dg, Df4);
                writepair(cv, p1, cadd(Df,Df4), csub(Df,Df4));
                writepair(cv, p2, cadd(Dg,Dg4), csub(Dg,Dg4));
            }
        }
        if (t == 0) {   // f = 2048 self-paired quad at positions (2,3)
            float4 K20 = make_float4(Kex[0].x, Kex[0].y, Kex[1].x, Kex[1].y);
            float2 b0,b1; readpair(cv, 2, b0, b1);
            float2 Ck=cadd(b0,b1), Cm=csub(b0,b1), Dk, Dm;
            pwmul(Ck, Cm, K20, getw(T1,T2,2048), Dk, Dm);
            writepair(cv, 2, cadd(Dk,Dm), csub(Dk,Dm));
        }
        __syncthreads();

        // I2: stages 1..4
#pragma unroll
        for (int k = 0; k < 16; ++k) r[k] = cv[swz(b3 + 2*k)];
        dit4(r, wd3);
#pragma unroll
        for (int k = 0; k < 16; ++k) cv[swz(b3 + 2*k)] = r[k];
        __syncthreads();
        // I3: stages 5..8
#pragma unroll
        for (int k = 0; k < 16; ++k) r[k] = cv[swz(b2 + 32*k)];
        dit4(r, wd2);
#pragma unroll
        for (int k = 0; k < 16; ++k) cv[swz(b2 + 32*k)] = r[k];
        __syncthreads();
        // I4: stages 9..12, write first half straight to global (bias folded into K)
#pragma unroll
        for (int k = 0; k < 16; ++k) r[k] = cv[swz(t + 512*k)];
        dit4(r, wd1);
#pragma unroll
        for (int k = 0; k < 8; ++k) yr[t + 512*k] = r[k];
        __syncthreads();
    }
}

extern "C" void kernel_launch(void* const* d_in, const int* in_sizes, int n_in,
                              void* d_out, int out_size, void* d_ws, size_t ws_size,
                              hipStream_t stream) {
    const float* x    = (const float*)d_in[0];
    const float* z    = (const float*)d_in[2];
    const float* W1   = (const float*)d_in[3];
    const float* b1   = (const float*)d_in[4];
    const float* W2   = (const float*)d_in[5];
    const float* b2   = (const float*)d_in[6];
    const float* W3   = (const float*)d_in[7];
    const float* b3   = (const float*)d_in[8];
    const float* Wout = (const float*)d_in[9];
    const float* freq = (const float*)d_in[10];
    const float* bias = (const float*)d_in[11];
    float* out = (float*)d_out;
    float* h3  = (float*)d_ws;   // 8192*16 floats = 512 KB

    hipLaunchKernelGGL(hyena_mlp, dim3(SEQ_LEN/256), dim3(256), 0, stream,
                       z, W1, b1, W2, b2, W3, b3, freq, h3);

    static bool attr_set = false;
    if (!attr_set) {
        (void)hipFuncSetAttribute((const void*)hyena_conv,
                                  hipFuncAttributeMaxDynamicSharedMemorySize,
                                  SMEM_BYTES);
        attr_set = true;
    }
    hipLaunchKernelGGL(hyena_conv, dim3(1024), dim3(NT), SMEM_BYTES, stream,
                       h3, Wout, x, bias, out);
}

// Round 7
// 523.305 us; speedup vs baseline: 1.2598x; 1.0681x over previous
//
#include <hip/hip_runtime.h>

#define NT 512
#define SEQ_LEN 8192

static __device__ __forceinline__ float2 f2(float x, float y){ return make_float2(x,y); }
static __device__ __forceinline__ float2 cadd(float2 a, float2 b){ return f2(a.x+b.x, a.y+b.y); }
static __device__ __forceinline__ float2 csub(float2 a, float2 b){ return f2(a.x-b.x, a.y-b.y); }
static __device__ __forceinline__ float2 cmul(float2 a, float2 b){ return f2(a.x*b.x-a.y*b.y, a.x*b.y+a.y*b.x); }
static __device__ __forceinline__ float2 cmulc(float2 a, float2 b){ return f2(a.x*b.x+a.y*b.y, a.y*b.x-a.x*b.y); } // a*conj(b)
static __device__ __forceinline__ float2 mul_mi(float2 a){ return f2(a.y, -a.x); }  // a * (-i)
static __device__ __forceinline__ float2 mul_pi(float2 a){ return f2(-a.y, a.x); }  // a * (+i)
static __device__ __forceinline__ int swz(int e){ return e ^ ((e>>4)&15) ^ ((e>>8)&15); }
static __device__ __forceinline__ int rev13(int v){ return (int)(__brev((unsigned)v) >> 19); }

// ---------------- MLP: h3[j][16] = sin-MLP(z[j]) ----------------
__global__ void hyena_mlp(const float* __restrict__ z,
                          const float* __restrict__ W1, const float* __restrict__ b1,
                          const float* __restrict__ W2, const float* __restrict__ b2,
                          const float* __restrict__ W3, const float* __restrict__ b3,
                          const float* __restrict__ freq,
                          float* __restrict__ h3) {
    int j = blockIdx.x * blockDim.x + threadIdx.x;
    if (j >= SEQ_LEN) return;
    float z0 = z[3*j+0], z1 = z[3*j+1], z2 = z[3*j+2];
    float ha[16], hb[16];
#pragma unroll
    for (int o = 0; o < 16; ++o) {
        float acc = b1[o] + z0*W1[o] + z1*W1[16+o] + z2*W1[32+o];
        ha[o] = sinf(freq[o] * acc);
    }
#pragma unroll
    for (int p = 0; p < 16; ++p) {
        float acc = b2[p];
#pragma unroll
        for (int o = 0; o < 16; ++o) acc += ha[o] * W2[o*16+p];
        hb[p] = sinf(freq[p] * acc);
    }
#pragma unroll
    for (int q = 0; q < 16; ++q) {
        float acc = b3[q];
#pragma unroll
        for (int o = 0; o < 16; ++o) acc += hb[o] * W3[o*16+q];
        h3[j*16+q] = sinf(freq[q] * acc);
    }
}

// ---- proj: k[d][j] = (h3[j]·Wout[:,d]) * exp(-t_j*|delta_d|), row-major [1024][8192] ----
#define PJ 128
__global__ void hyena_proj(const float* __restrict__ h3, const float* __restrict__ Wout,
                           float* __restrict__ krows) {
    __shared__ float sW[16][1024];     // 64 KB
    __shared__ float sh[PJ][17];       // padded: (j*17+o)%32 varies -> no 16-way conflict
    const int t = threadIdx.x;         // 256
    const int jb = blockIdx.x * PJ;
    for (int i = t; i < 16*1024; i += 256) sW[i>>10][i&1023] = Wout[i];
    for (int i = t; i < PJ*16; i += 256)   sh[i>>4][i&15]    = h3[(size_t)(jb + (i>>4))*16 + (i&15)];
    __syncthreads();
    const float dmin = -3.0701134573253941f;   // log(0.01)/1.5
    const float dmax = -15.350567286626971f;   // log(0.01)/0.3
    const int jloc = t & 127;
    const int dloc = t >> 7;
    const float tj = (float)(jb + jloc) * (1.0f/8191.0f);
#pragma unroll 1
    for (int db = 0; db < 1024; db += 2) {
        int d = db + dloc;
        float absd = fabsf(dmin + (dmax - dmin) * ((float)d * (1.0f/1023.0f)));
        float acc = 0.f;
#pragma unroll
        for (int o = 0; o < 16; ++o) acc += sh[jloc][o] * sW[o][d];
        krows[(size_t)d*SEQ_LEN + jb + jloc] = acc * __expf(-tj * absd);
    }
}

// ------ 4-stage (radix-16-as-radix-2^4) register butterflies, slim twiddles ------
static __device__ __forceinline__ void dif4(float2 r[16], float2 wd){
    const float2 c1 = f2(0.9238795325112867f,-0.3826834323650898f);  // e^{-i pi/8}
    const float2 c2 = f2(0.7071067811865476f,-0.7071067811865476f);  // e^{-i pi/4}
    const float2 c3 = f2(0.3826834323650898f,-0.9238795325112867f);  // e^{-i 3pi/8}
    float2 wc = cmul(wd,wd), wb = cmul(wc,wc), wa = cmul(wb,wb);
    float2 t0 = wd, t1 = cmul(wd,c1), t2 = cmul(wd,c2), t3 = cmul(wd,c3);
    float2 u0 = wc, u1 = cmul(wc,c2);
    { float2 u=r[0], v=r[8];  r[0]=cadd(u,v); r[8] =cmul(csub(u,v), t0); }
    { float2 u=r[1], v=r[9];  r[1]=cadd(u,v); r[9] =cmul(csub(u,v), t1); }
    { float2 u=r[2], v=r[10]; r[2]=cadd(u,v); r[10]=cmul(csub(u,v), t2); }
    { float2 u=r[3], v=r[11]; r[3]=cadd(u,v); r[11]=cmul(csub(u,v), t3); }
    { float2 u=r[4], v=r[12]; r[4]=cadd(u,v); r[12]=mul_mi(cmul(csub(u,v), t0)); }
    { float2 u=r[5], v=r[13]; r[5]=cadd(u,v); r[13]=mul_mi(cmul(csub(u,v), t1)); }
    { float2 u=r[6], v=r[14]; r[6]=cadd(u,v); r[14]=mul_mi(cmul(csub(u,v), t2)); }
    { float2 u=r[7], v=r[15]; r[7]=cadd(u,v); r[15]=mul_mi(cmul(csub(u,v), t3)); }
#pragma unroll
    for (int b = 0; b < 16; b += 8) {
        { float2 u=r[b+0], v=r[b+4]; r[b+0]=cadd(u,v); r[b+4]=cmul(csub(u,v), u0); }
        { float2 u=r[b+1], v=r[b+5]; r[b+1]=cadd(u,v); r[b+5]=cmul(csub(u,v), u1); }
        { float2 u=r[b+2], v=r[b+6]; r[b+2]=cadd(u,v); r[b+6]=mul_mi(cmul(csub(u,v), u0)); }
        { float2 u=r[b+3], v=r[b+7]; r[b+3]=cadd(u,v); r[b+7]=mul_mi(cmul(csub(u,v), u1)); }
    }
#pragma unroll
    for (int b = 0; b < 16; b += 4) {
        { float2 u=r[b+0], v=r[b+2]; r[b+0]=cadd(u,v); r[b+2]=cmul(csub(u,v), wb); }
        { float2 u=r[b+1], v=r[b+3]; r[b+1]=cadd(u,v); r[b+3]=mul_mi(cmul(csub(u,v), wb)); }
    }
#pragma unroll
    for (int b = 0; b < 16; b += 2) { float2 u=r[b], v=r[b+1]; r[b]=cadd(u,v); r[b+1]=cmul(csub(u,v), wa); }
}
static __device__ __forceinline__ void dit4(float2 r[16], float2 wd){
    const float2 c1 = f2(0.9238795325112867f,-0.3826834323650898f);
    const float2 c2 = f2(0.7071067811865476f,-0.7071067811865476f);
    const float2 c3 = f2(0.3826834323650898f,-0.9238795325112867f);
    float2 wc = cmul(wd,wd), wb = cmul(wc,wc), wa = cmul(wb,wb);
    float2 t0 = wd, t1 = cmul(wd,c1), t2 = cmul(wd,c2), t3 = cmul(wd,c3);
    float2 u0 = wc, u1 = cmul(wc,c2);
#pragma unroll
    for (int b = 0; b < 16; b += 2) { float2 u=r[b]; float2 t=cmulc(r[b+1], wa); r[b]=cadd(u,t); r[b+1]=csub(u,t); }
#pragma unroll
    for (int b = 0; b < 16; b += 4) {
        { float2 u=r[b+0]; float2 t=cmulc(r[b+2], wb);         r[b+0]=cadd(u,t); r[b+2]=csub(u,t); }
        { float2 u=r[b+1]; float2 t=mul_pi(cmulc(r[b+3], wb)); r[b+1]=cadd(u,t); r[b+3]=csub(u,t); }
    }
#pragma unroll
    for (int b = 0; b < 16; b += 8) {
        { float2 u=r[b+0]; float2 t=cmulc(r[b+4], u0);         r[b+0]=cadd(u,t); r[b+4]=csub(u,t); }
        { float2 u=r[b+1]; float2 t=cmulc(r[b+5], u1);         r[b+1]=cadd(u,t); r[b+5]=csub(u,t); }
        { float2 u=r[b+2]; float2 t=mul_pi(cmulc(r[b+6], u0)); r[b+2]=cadd(u,t); r[b+6]=csub(u,t); }
        { float2 u=r[b+3]; float2 t=mul_pi(cmulc(r[b+7], u1)); r[b+3]=cadd(u,t); r[b+7]=csub(u,t); }
    }
    { float2 u=r[0]; float2 t=cmulc(r[8],  t0);        r[0]=cadd(u,t); r[8] =csub(u,t); }
    { float2 u=r[1]; float2 t=cmulc(r[9],  t1);        r[1]=cadd(u,t); r[9] =csub(u,t); }
    { float2 u=r[2]; float2 t=cmulc(r[10], t2);        r[2]=cadd(u,t); r[10]=csub(u,t); }
    { float2 u=r[3]; float2 t=cmulc(r[11], t3);        r[3]=cadd(u,t); r[11]=csub(u,t); }
    { float2 u=r[4]; float2 t=mul_pi(cmulc(r[12], t0)); r[4]=cadd(u,t); r[12]=csub(u,t); }
    { float2 u=r[5]; float2 t=mul_pi(cmulc(r[13], t1)); r[5]=cadd(u,t); r[13]=csub(u,t); }
    { float2 u=r[6]; float2 t=mul_pi(cmulc(r[14], t2)); r[6]=cadd(u,t); r[14]=csub(u,t); }
    { float2 u=r[7]; float2 t=mul_pi(cmulc(r[15], t3)); r[7]=cadd(u,t); r[15]=csub(u,t); }
}

// aligned pair access (positions p even; swz may flip parity, so select)
static __device__ __forceinline__ void readpair(const float2* cv, int p, float2& e0, float2& e1){
    int sp = swz(p);
    float4 q = *(const float4*)&cv[sp & ~1];
    float2 lo = f2(q.x,q.y), hi = f2(q.z,q.w);
    if (sp & 1) { e0 = hi; e1 = lo; } else { e0 = lo; e1 = hi; }
}
static __device__ __forceinline__ void writepair(float2* cv, int p, float2 e0, float2 e1){
    int sp = swz(p);
    float4 q;
    if (sp & 1) q = make_float4(e1.x,e1.y,e0.x,e0.y);
    else        q = make_float4(e0.x,e0.y,e1.x,e1.y);
    *(float4*)&cv[sp & ~1] = q;
}

static __device__ __forceinline__ float2 getw(const float2* T1, const float2* T2, int k){
    return cmul(T1[k>>6], T2[k&63]);   // e^{-i pi k / 8192}
}
static __device__ __forceinline__ float4 kpack(float2 Ck, float2 Cm, float2 w, float bds){
    const float s = 1.0f/16384.0f;
    float2 A  = f2(0.5f*(Ck.x+Cm.x), 0.5f*(Ck.y-Cm.y));
    float2 Bc = f2(0.5f*(Ck.x-Cm.x), 0.5f*(Ck.y+Cm.y));
    float2 B  = f2(Bc.y, -Bc.x);
    float2 wB = cmul(w, B);
    return make_float4((A.x+wB.x)*s + bds, (A.y+wB.y)*s,
                       (A.x-wB.x)*s + bds, -((A.y-wB.y)*s));
}
static __device__ __forceinline__ void pwmul(float2 Ck, float2 Cm, float4 Kp, float2 w,
                                             float2& Dk, float2& Dm){
    float2 A  = f2(0.5f*(Ck.x+Cm.x), 0.5f*(Ck.y-Cm.y));
    float2 Bc = f2(0.5f*(Ck.x-Cm.x), 0.5f*(Ck.y+Cm.y));
    float2 B  = f2(Bc.y, -Bc.x);
    float2 wB = cmul(w, B);
    float2 Xk = f2(A.x+wB.x, A.y+wB.y);
    float2 Xm = f2(A.x-wB.x, -(A.y-wB.y));
    float2 Yk = cmul(Xk, f2(Kp.x,Kp.y));
    float2 Ym = cmul(Xm, f2(Kp.z,Kp.w));
    float2 A2 = f2(Yk.x+Ym.x, Yk.y-Ym.y);
    float2 Bt = f2(Yk.x-Ym.x, Yk.y+Ym.y);
    float2 B2 = cmulc(Bt, w);
    Dk = f2(A2.x - B2.y, A2.y + B2.x);
    Dm = f2(A2.x + B2.y, B2.x - A2.y);
}

// LDS: cv 8192 | tab 512 | T1 64 | T2 64 | Kex 2 | pad 2 | KA 4096 | KB 4096 = 17028 f2
#define SMEM_BYTES (17028 * 8)

// Spill control: every loop that does NOT index r[16] is forced unroll-1 so the
// scheduler can't software-pipeline 4 iterations' live sets past the 128-VGPR cap.
// r[16] loops stay fully unrolled (static indexing, else scratch — rule #20).
template<bool USE_K>
__global__ __launch_bounds__(NT, 1)
void hyena_conv(const float* __restrict__ h3g, const float* __restrict__ Wout,
                const float* __restrict__ krows,
                const float* __restrict__ x, const float* __restrict__ bias,
                float* __restrict__ out) {
    extern __shared__ float2 smem[];
    float2* cv  = smem;                 // 8192
    float2* tab = cv + 8192;            // 512: e^{-i pi p/4096}
    float2* T1  = tab + 512;            // 64:  e^{-i pi h/128}
    float2* T2  = T1 + 64;              // 64:  e^{-i pi l/8192}
    float2* Kex = T2 + 64;              // 2:   K-pack for f=2048 (lane-0 only)
    float4* KA  = (float4*)(Kex + 4);   // 2048 f4
    float4* KB  = KA + 2048;            // 2048 f4
    const int t = threadIdx.x;
    const int d = blockIdx.x;
    const float PI = 3.14159265358979323846f;

    { float s_,c_; sincosf((PI/4096.0f)*(float)t, &s_, &c_); tab[t] = f2(c_, -s_); }
    if (t < 64)       { float s_,c_; sincosf((PI/128.0f)*(float)t, &s_,&c_); T1[t] = f2(c_,-s_); }
    else if (t < 128) { int l=t-64; float s_,c_; sincosf((PI/8192.0f)*(float)l,&s_,&c_); T2[l] = f2(c_,-s_); }
    __syncthreads();

    const float2 wd1 = tab[t];            // pass stride 512
    const float2 wd2 = tab[(t&31)<<4];    // pass stride 32
    const float2 wd3 = tab[(t&1)<<8];     // pass stride 2
    const int b2 = ((t>>5)<<9) | (t&31);
    const int b3 = ((t>>1)<<5) | (t&1);

    const float bds = bias[d] * (1.0f/16384.0f);

    float2 r[16];
    if (USE_K) {
        const float2* kr = (const float2*)(krows + (size_t)d * SEQ_LEN);
#pragma unroll
        for (int k = 0; k < 8; ++k) r[k] = kr[t + 512*k];
    } else {
        const float dmin = -3.0701134573253941f;   // log(0.01)/1.5
        const float dmax = -15.350567286626971f;   // log(0.01)/0.3
        const float absd = fabsf(dmin + (dmax - dmin) * ((float)d * (1.0f/1023.0f)));
        float wcol[16];
#pragma unroll
        for (int o = 0; o < 16; ++o) wcol[o] = Wout[o*1024 + d];
#pragma unroll
        for (int k = 0; k < 8; ++k) {
            int e = t + 512*k;
            const float4* h4 = (const float4*)(h3g + (size_t)(2*e)*16);
            float a0 = 0.f, a1 = 0.f;
#pragma unroll
            for (int v4 = 0; v4 < 4; ++v4) {
                float4 q0 = h4[v4], q1 = h4[4+v4];
                a0 += q0.x*wcol[4*v4] + q0.y*wcol[4*v4+1] + q0.z*wcol[4*v4+2] + q0.w*wcol[4*v4+3];
                a1 += q1.x*wcol[4*v4] + q1.y*wcol[4*v4+1] + q1.z*wcol[4*v4+2] + q1.w*wcol[4*v4+3];
            }
            float ta = (float)(2*e)   * (1.0f/8191.0f);
            float tb = (float)(2*e+1) * (1.0f/8191.0f);
            r[k] = f2(a0 * __expf(-ta*absd), a1 * __expf(-tb*absd));
        }
    }
#pragma unroll
    for (int k = 8; k < 16; ++k) r[k] = f2(0.f, 0.f);

    dif4(r, wd1);
#pragma unroll
    for (int k = 0; k < 16; ++k) cv[swz(t + 512*k)] = r[k];
    __syncthreads();
#pragma unroll
    for (int k = 0; k < 16; ++k) r[k] = cv[swz(b2 + 32*k)];
    dif4(r, wd2);
#pragma unroll
    for (int k = 0; k < 16; ++k) cv[swz(b2 + 32*k)] = r[k];
    __syncthreads();
#pragma unroll
    for (int k = 0; k < 16; ++k) r[k] = cv[swz(b3 + 2*k)];
    dif4(r, wd3);
#pragma unroll
    for (int k = 0; k < 16; ++k) cv[swz(b3 + 2*k)] = r[k];
    __syncthreads();

    // unpack rfft(K) -> packed spectrum in LDS
#pragma unroll 1
    for (int q = 0; q < 4; ++q) {
        int f = t + 512*q;
        if (f == 0) {
            float2 a0,a1; readpair(cv, 0, a0, a1);
            float2 C0 = cadd(a0,a1), C4 = csub(a0,a1);
            const float s = 1.0f/16384.0f;
            KA[0] = make_float4((C0.x+C0.y)*s + bds, (C0.x-C0.y)*s + bds, C4.x*s + bds, -C4.y*s);
            KB[0] = make_float4(0.f,0.f,0.f,0.f);
        } else {
            int g = 4096 - f;
            float2 a0,a1,b0,b1;
            readpair(cv, rev13(f), a0, a1);
            readpair(cv, rev13(g), b0, b1);
            float2 Cf=cadd(a0,a1), Cf4=csub(a0,a1), Cg=cadd(b0,b1), Cg4=csub(b0,b1);
            KA[q*NT + t] = kpack(Cf, Cg4, getw(T1,T2,f), bds);
            KB[q*NT + t] = kpack(Cg, Cf4, getw(T1,T2,g), bds);
        }
    }
    if (t == 0) {
        float2 b0,b1; readpair(cv, 2, b0, b1);   // rev13(2048) = 2
        float4 K20 = kpack(cadd(b0,b1), csub(b0,b1), getw(T1,T2,2048), bds);
        Kex[0] = f2(K20.x, K20.y);
        Kex[1] = f2(K20.z, K20.w);
    }
    __syncthreads();

    // ---- batches ----
#pragma unroll 1
    for (int b = 0; b < 4; ++b) {
        const float2* xr = (const float2*)(x + ((size_t)b*1024 + d)*SEQ_LEN);
        float2* yr = (float2*)(out + ((size_t)b*1024 + d)*SEQ_LEN);

#pragma unroll
        for (int k = 0; k < 8; ++k) r[k] = xr[t + 512*k];
#pragma unroll
        for (int k = 8; k < 16; ++k) r[k] = f2(0.f,0.f);
        dif4(r, wd1);
#pragma unroll
        for (int k = 0; k < 16; ++k) cv[swz(t + 512*k)] = r[k];
        __syncthreads();
#pragma unroll
        for (int k = 0; k < 16; ++k) r[k] = cv[swz(b2 + 32*k)];
        dif4(r, wd2);
#pragma unroll
        for (int k = 0; k < 16; ++k) cv[swz(b2 + 32*k)] = r[k];
        __syncthreads();
#pragma unroll
        for (int k = 0; k < 16; ++k) r[k] = cv[swz(b3 + 2*k)];
        dif4(r, wd3);
#pragma unroll
        for (int k = 0; k < 16; ++k) cv[swz(b3 + 2*k)] = r[k];
        __syncthreads();

        // FUSED: fwd stage 0 + rfft-unpack * K + repack + inv stage 0
#pragma unroll 1
        for (int q = 0; q < 4; ++q) {
            int f = t + 512*q;
            float4 Kpa = KA[q*NT + t];
            if (f == 0) {
                float2 a0,a1; readpair(cv, 0, a0, a1);
                float2 C0 = cadd(a0,a1), C4 = csub(a0,a1);
                float R0 = C0.x + C0.y, RN = C0.x - C0.y;
                float Y0 = R0 * Kpa.x, YN = RN * Kpa.y;
                float2 D0 = f2(Y0+YN, Y0-YN);
                float2 Y4 = cmul(f2(C4.x,-C4.y), f2(Kpa.z, Kpa.w));
                float2 D4 = f2(2.f*Y4.x, -2.f*Y4.y);
                writepair(cv, 0, cadd(D0,D4), csub(D0,D4));
            } else {
                float4 Kpb = KB[q*NT + t];
                int g = 4096 - f;
                int p1 = rev13(f), p2 = rev13(g);
                float2 a0,a1,b0,b1;
                readpair(cv, p1, a0, a1);
                readpair(cv, p2, b0, b1);
                float2 Cf=cadd(a0,a1), Cf4=csub(a0,a1), Cg=cadd(b0,b1), Cg4=csub(b0,b1);
                float2 Df,Dg4,Dg,Df4;
                pwmul(Cf, Cg4, Kpa, getw(T1,T2,f), Df, Dg4);
                pwmul(Cg, Cf4, Kpb, getw(T1,T2,g), Dg, Df4);
                writepair(cv, p1, cadd(Df,Df4), csub(Df,Df4));
                writepair(cv, p2, cadd(Dg,Dg4), csub(Dg,Dg4));
            }
        }
        if (t == 0) {   // f = 2048 self-paired quad at positions (2,3)
            float4 K20 = make_float4(Kex[0].x, Kex[0].y, Kex[1].x, Kex[1].y);
            float2 b0,b1; readpair(cv, 2, b0, b1);
            float2 Ck=cadd(b0,b1), Cm=csub(b0,b1), Dk, Dm;
            pwmul(Ck, Cm, K20, getw(T1,T2,2048), Dk, Dm);
            writepair(cv, 2, cadd(Dk,Dm), csub(Dk,Dm));
        }
        __syncthreads();

#pragma unroll
        for (int k = 0; k < 16; ++k) r[k] = cv[swz(b3 + 2*k)];
        dit4(r, wd3);
#pragma unroll
        for (int k = 0; k < 16; ++k) cv[swz(b3 + 2*k)] = r[k];
        __syncthreads();
#pragma unroll
        for (int k = 0; k < 16; ++k) r[k] = cv[swz(b2 + 32*k)];
        dit4(r, wd2);
#pragma unroll
        for (int k = 0; k < 16; ++k) cv[swz(b2 + 32*k)] = r[k];
        __syncthreads();
#pragma unroll
        for (int k = 0; k < 16; ++k) r[k] = cv[swz(t + 512*k)];
        dit4(r, wd1);
#pragma unroll
        for (int k = 0; k < 8; ++k) yr[t + 512*k] = r[k];
        __syncthreads();
    }
}

extern "C" void kernel_launch(void* const* d_in, const int* in_sizes, int n_in,
                              void* d_out, int out_size, void* d_ws, size_t ws_size,
                              hipStream_t stream) {
    const float* x    = (const float*)d_in[0];
    const float* z    = (const float*)d_in[2];
    const float* W1   = (const float*)d_in[3];
    const float* b1   = (const float*)d_in[4];
    const float* W2   = (const float*)d_in[5];
    const float* b2   = (const float*)d_in[6];
    const float* W3   = (const float*)d_in[7];
    const float* b3   = (const float*)d_in[8];
    const float* Wout = (const float*)d_in[9];
    const float* freq = (const float*)d_in[10];
    const float* bias = (const float*)d_in[11];
    float* out = (float*)d_out;
    float* h3  = (float*)d_ws;                                  // 512 KB
    float* krows = (float*)((char*)d_ws + 512*1024);            // 32 MB

    const size_t need = 512*1024 + (size_t)32*1024*1024;
    const bool use_k = ws_size >= need;

    hipLaunchKernelGGL(hyena_mlp, dim3(SEQ_LEN/256), dim3(256), 0, stream,
                       z, W1, b1, W2, b2, W3, b3, freq, h3);

    static bool attr_set = false;
    if (!attr_set) {
        (void)hipFuncSetAttribute((const void*)hyena_conv<true>,
                                  hipFuncAttributeMaxDynamicSharedMemorySize, SMEM_BYTES);
        (void)hipFuncSetAttribute((const void*)hyena_conv<false>,
                                  hipFuncAttributeMaxDynamicSharedMemorySize, SMEM_BYTES);
        attr_set = true;
    }

    if (use_k) {
        hipLaunchKernelGGL(hyena_proj, dim3(SEQ_LEN/PJ), dim3(256), 0, stream,
                           h3, Wout, krows);
        hipLaunchKernelGGL(hyena_conv<true>, dim3(1024), dim3(NT), SMEM_BYTES, stream,
                           h3, Wout, krows, x, bias, out);
    } else {
        hipLaunchKernelGGL(hyena_conv<false>, dim3(1024), dim3(NT), SMEM_BYTES, stream,
                           h3, Wout, krows, x, bias, out);
    }
}